// Round 4
// baseline (1373.698 us; speedup 1.0000x reference)
//
#include <hip/hip_runtime.h>

#define NNET 32
#define NUNITS 2048
#define NEXC 1638
#define NINH 410

// ---------------------------------------------------------------------------
// Jobs 1-4, linear streaming: acc[n,q] += sum_p W[n,p,q] * r[n,p].
// Block = (n, p-chunk). The block reads its [PCH x Q] row-panel CONTIGUOUSLY
// (consecutive rows are adjacent in memory), 8B/lane float2 loads. Thread t
// keeps float2 columns {t, t+256, ...} (NC registers pairs) and does one
// atomicAdd pair per column at the end.
// ---------------------------------------------------------------------------
template<int Q2, int NC>   // Q2 = Q/2 (float2 count per row); NC = ceil(Q2/256)
__device__ __forceinline__ void row_matvec(const float* __restrict__ W,
                                           const float* __restrict__ r,
                                           float* __restrict__ acc,
                                           int rel_blk, int P, int PB, int PCH,
                                           int qoff, int vecoff) {
    int n  = rel_blk / PB;
    int pb = rel_blk % PB;
    int p0 = pb * PCH;
    int len = min(PCH, P - p0);
    int t = threadIdx.x;

    __shared__ float s_r[256];            // PCH <= 205
    if (t < len) s_r[t] = r[n * NUNITS + vecoff + p0 + t];
    __syncthreads();

    float ax[NC], ay[NC];
    #pragma unroll
    for (int k = 0; k < NC; ++k) { ax[k] = 0.f; ay[k] = 0.f; }

    const float* base = W + ((size_t)n * P + p0) * (size_t)(2 * Q2);
    #pragma unroll 2
    for (int p = 0; p < len; ++p) {
        const float2* row2 = (const float2*)(base + (size_t)p * (size_t)(2 * Q2));
        float rp = s_r[p];
        #pragma unroll
        for (int k = 0; k < NC; ++k) {
            int c = k * 256 + t;
            if (NC * 256 == Q2 || c < Q2) {
                float2 w = row2[c];
                ax[k] += w.x * rp;
                ay[k] += w.y * rp;
            }
        }
    }

    float* outp = acc + n * NUNITS + qoff;
    #pragma unroll
    for (int k = 0; k < NC; ++k) {
        int c = k * 256 + t;
        if (c < Q2) {
            atomicAdd(&outp[2 * c],     ax[k]);
            atomicAdd(&outp[2 * c + 1], ay[k]);
        }
    }
}

// ---------------------------------------------------------------------------
// Job 5: inter_inh[i,a] = sum_{j,b} W_inter[i,j,a,b] * r[i, NEXC+b]
// Block = (i, j, half): streams a contiguous 205x410-float chunk (336 KB).
// 4 waves round-robin consecutive rows; lanes stride float2; shfl-reduce.
// ---------------------------------------------------------------------------
__device__ __forceinline__ void inter_ij(const float* __restrict__ Wint,
                                         const float* __restrict__ r,
                                         float* __restrict__ acc,
                                         int rel_blk) {
    int i    = rel_blk >> 6;          // /64
    int j    = (rel_blk >> 1) & 31;
    int half = rel_blk & 1;

    __shared__ float s_ri[NINH];
    for (int t = threadIdx.x; t < NINH; t += 256)
        s_ri[t] = r[i * NUNITS + NEXC + t];   // einsum 'ijab,ib->ia': r of network i
    __syncthreads();

    int wave = threadIdx.x >> 6;
    int lane = threadIdx.x & 63;

    const float* plane = Wint + (size_t)(i * NNET + j) * NINH * NINH;
    int a0 = half * 205;
    int a1 = a0 + 205;                 // 410 = 2*205
    for (int a = a0 + wave; a < a1; a += 4) {
        const float2* row2 = (const float2*)(plane + (size_t)a * NINH);
        float s = 0.f;
        for (int b2 = lane; b2 < NINH / 2; b2 += 64) {   // 205 float2s
            float2 w = row2[b2];
            s += w.x * s_ri[2 * b2] + w.y * s_ri[2 * b2 + 1];
        }
        for (int off = 32; off; off >>= 1)
            s += __shfl_down(s, off, 64);
        if (lane == 0)
            atomicAdd(&acc[i * NUNITS + NEXC + a], s);
    }
}

// ---------------------------------------------------------------------------
// Fused kernel. Flat grid, 2688 blocks (big 1.34MB blocks first for balance):
//   [0,256)     W_ee: PB=8   (1.34 MB/block)
//   [256,320)   W_ie: PB=2   (1.34 MB/block)
//   [320,576)   W_ei: PB=8   (336 KB/block)
//   [576,640)   W_ii: PB=2   (336 KB/block)
//   [640,2688)  W_inter: 32*32*2 half-planes (336 KB/block)
// ---------------------------------------------------------------------------
__global__ __launch_bounds__(256) void fused_matvec(
    const float* __restrict__ Wee, const float* __restrict__ Wei,
    const float* __restrict__ Wie, const float* __restrict__ Wii,
    const float* __restrict__ Wint,
    const float* __restrict__ r, float* __restrict__ acc) {
    int blk = blockIdx.x;
    if (blk < 256) {
        row_matvec<819, 4>(Wee, r, acc, blk,       1638, 8, 205, 0,    0);
    } else if (blk < 320) {
        row_matvec<819, 4>(Wie, r, acc, blk - 256,  410, 2, 205, 0,    NEXC);
    } else if (blk < 576) {
        row_matvec<205, 1>(Wei, r, acc, blk - 320, 1638, 8, 205, NEXC, 0);
    } else if (blk < 640) {
        row_matvec<205, 1>(Wii, r, acc, blk - 576,  410, 2, 205, NEXC, NEXC);
    } else {
        inter_ij(Wint, r, acc, blk - 640);
    }
}

// ---------------------------------------------------------------------------
// Finalize: r_new = 0.9*r + 0.1*relu(acc + unit_input)
// ---------------------------------------------------------------------------
__global__ __launch_bounds__(256) void finalize_kernel(
    const float* __restrict__ r, const float* __restrict__ uin,
    const float* __restrict__ acc, float* __restrict__ out) {
    int idx = blockIdx.x * 256 + threadIdx.x;
    if (idx < NNET * NUNITS) {
        float total = acc[idx] + uin[idx];
        float phi = fmaxf(total, 0.f);
        out[idx] = 0.9f * r[idx] + 0.1f * phi;
    }
}

extern "C" void kernel_launch(void* const* d_in, const int* in_sizes, int n_in,
                              void* d_out, int out_size, void* d_ws, size_t ws_size,
                              hipStream_t stream) {
    const float* unit_input = (const float*)d_in[0];
    const float* r          = (const float*)d_in[1];
    const float* W_ee       = (const float*)d_in[2];
    const float* W_ei       = (const float*)d_in[3];
    const float* W_ie       = (const float*)d_in[4];
    const float* W_ii       = (const float*)d_in[5];
    const float* W_inter    = (const float*)d_in[6];
    float* out = (float*)d_out;
    float* acc = (float*)d_ws;  // 32*2048 floats = 256 KB

    hipMemsetAsync(acc, 0, NNET * NUNITS * sizeof(float), stream);

    fused_matvec<<<2688, 256, 0, stream>>>(W_ee, W_ei, W_ie, W_ii, W_inter, r, acc);

    finalize_kernel<<<(NNET * NUNITS + 255) / 256, 256, 0, stream>>>(r, unit_input, acc, out);
}

// Round 5
// 1200.752 us; speedup vs baseline: 1.1440x; 1.1440x over previous
//
#include <hip/hip_runtime.h>

#define NNET 32
#define NUNITS 2048
#define NEXC 1638
#define NINH 410

// ---------------------------------------------------------------------------
// Jobs 1-4: acc[n,q] += sum_p W[n,p,q] * r[n,p]   (q contiguous within a row)
// Thread t owns float2 column c = qb*256+t. Coalesced 512B/wave-instr.
// Inner loop: EIGHT NAMED float2 loads per batch -> 64B in flight per thread.
// ---------------------------------------------------------------------------
__device__ __forceinline__ void col_matvec(const float* __restrict__ W,
                                           const float* __restrict__ r,
                                           float* __restrict__ acc,
                                           int rel_blk,
                                           int P, int Q, int QB, int PB, int PCH,
                                           int qoff, int vecoff) {
    int n   = rel_blk / (QB * PB);
    int rem = rel_blk % (QB * PB);
    int qb  = rem / PB;
    int pb  = rem % PB;

    int p0  = pb * PCH;
    int len = min(PCH, P - p0);
    int t   = threadIdx.x;

    __shared__ float s_r[256];            // PCH <= 205
    if (t < len) s_r[t] = r[n * NUNITS + vecoff + p0 + t];
    __syncthreads();

    int Q2 = Q >> 1;                      // float2s per row (compile-time after inline)
    int c  = qb * 256 + t;
    if (c >= Q2) return;

    const float2* Wp  = (const float2*)(W + ((size_t)n * P + p0) * Q) + c;
    const size_t step = (size_t)Q2;

    float ax = 0.f, ay = 0.f;
    int p = 0;
    for (; p + 8 <= len; p += 8) {
        const float2* b = Wp + (size_t)p * step;
        float2 w0 = b[0 * step];
        float2 w1 = b[1 * step];
        float2 w2 = b[2 * step];
        float2 w3 = b[3 * step];
        float2 w4 = b[4 * step];
        float2 w5 = b[5 * step];
        float2 w6 = b[6 * step];
        float2 w7 = b[7 * step];
        ax += w0.x * s_r[p + 0] + w1.x * s_r[p + 1] + w2.x * s_r[p + 2] + w3.x * s_r[p + 3]
            + w4.x * s_r[p + 4] + w5.x * s_r[p + 5] + w6.x * s_r[p + 6] + w7.x * s_r[p + 7];
        ay += w0.y * s_r[p + 0] + w1.y * s_r[p + 1] + w2.y * s_r[p + 2] + w3.y * s_r[p + 3]
            + w4.y * s_r[p + 4] + w5.y * s_r[p + 5] + w6.y * s_r[p + 6] + w7.y * s_r[p + 7];
    }
    for (; p < len; ++p) {
        float2 w = Wp[(size_t)p * step];
        ax += w.x * s_r[p];
        ay += w.y * s_r[p];
    }

    atomicAdd(&acc[n * NUNITS + qoff + 2 * c],     ax);
    atomicAdd(&acc[n * NUNITS + qoff + 2 * c + 1], ay);
}

// ---------------------------------------------------------------------------
// Job 5: inter_inh[i,a] = sum_{j,b} W_inter[i,j,a,b] * r[i, NEXC+b]
// Block = (i, j, half-plane): contiguous 336KB chunk. Wave-per-row dot, FOUR
// named float2 loads per row, TWO rows in flight, interleaved shfl reduce.
// ---------------------------------------------------------------------------
__device__ __forceinline__ float row_dot(const float2* __restrict__ row2,
                                         const float* __restrict__ s_ri, int lane) {
    // 205 float2s: lane, lane+64, lane+128 always valid; lane+192 iff lane<13
    float2 w0 = row2[lane];
    float2 w1 = row2[lane + 64];
    float2 w2 = row2[lane + 128];
    float s = w0.x * s_ri[2 * lane]       + w0.y * s_ri[2 * lane + 1]
            + w1.x * s_ri[2 * lane + 128] + w1.y * s_ri[2 * lane + 129]
            + w2.x * s_ri[2 * lane + 256] + w2.y * s_ri[2 * lane + 257];
    if (lane < 13) {
        float2 w3 = row2[lane + 192];
        s += w3.x * s_ri[2 * lane + 384] + w3.y * s_ri[2 * lane + 385];
    }
    return s;
}

__device__ __forceinline__ void inter_ij(const float* __restrict__ Wint,
                                         const float* __restrict__ r,
                                         float* __restrict__ acc,
                                         int rel_blk) {
    int i    = rel_blk >> 6;          // /64
    int j    = (rel_blk >> 1) & 31;
    int half = rel_blk & 1;

    __shared__ float s_ri[NINH];
    for (int t = threadIdx.x; t < NINH; t += 256)
        s_ri[t] = r[i * NUNITS + NEXC + t];   // einsum 'ijab,ib->ia': r of network i
    __syncthreads();

    int wave = threadIdx.x >> 6;
    int lane = threadIdx.x & 63;

    const float* plane = Wint + (size_t)(i * NNET + j) * NINH * NINH;
    float* outp = acc + i * NUNITS + NEXC;
    int a0 = half * 205;
    int a1 = a0 + 205;                 // 410 = 2*205

    for (int a = a0 + wave; a < a1; a += 8) {   // rows a and a+4 together
        int aB = a + 4;
        bool hasB = aB < a1;                    // wave-uniform
        float sA = row_dot((const float2*)(plane + (size_t)a * NINH), s_ri, lane);
        float sB = hasB ? row_dot((const float2*)(plane + (size_t)aB * NINH), s_ri, lane) : 0.f;
        for (int off = 32; off; off >>= 1) {
            sA += __shfl_down(sA, off, 64);
            sB += __shfl_down(sB, off, 64);
        }
        if (lane == 0) {
            atomicAdd(&outp[a], sA);
            if (hasB) atomicAdd(&outp[aB], sB);
        }
    }
}

// ---------------------------------------------------------------------------
// Fused kernel. Flat grid, 3648 blocks:
//   [0,1024)     W_ee:   QB=4, PB=8
//   [1024,1280)  W_ie:   QB=4, PB=2
//   [1280,1536)  W_ei:   QB=1, PB=8
//   [1536,1600)  W_ii:   QB=1, PB=2
//   [1600,3648)  W_inter: 32*32*2 contiguous half-planes
// ---------------------------------------------------------------------------
__global__ __launch_bounds__(256) void fused_matvec(
    const float* __restrict__ Wee, const float* __restrict__ Wei,
    const float* __restrict__ Wie, const float* __restrict__ Wii,
    const float* __restrict__ Wint,
    const float* __restrict__ r, float* __restrict__ acc) {
    int blk = blockIdx.x;
    if (blk < 1024) {
        col_matvec(Wee, r, acc, blk,        1638, 1638, 4, 8, 205, 0,    0);
    } else if (blk < 1280) {
        col_matvec(Wie, r, acc, blk - 1024,  410, 1638, 4, 2, 205, 0,    NEXC);
    } else if (blk < 1536) {
        col_matvec(Wei, r, acc, blk - 1280, 1638,  410, 1, 8, 205, NEXC, 0);
    } else if (blk < 1600) {
        col_matvec(Wii, r, acc, blk - 1536,  410,  410, 1, 2, 205, NEXC, NEXC);
    } else {
        inter_ij(Wint, r, acc, blk - 1600);
    }
}

// ---------------------------------------------------------------------------
// Finalize: r_new = 0.9*r + 0.1*relu(acc + unit_input)
// ---------------------------------------------------------------------------
__global__ __launch_bounds__(256) void finalize_kernel(
    const float* __restrict__ r, const float* __restrict__ uin,
    const float* __restrict__ acc, float* __restrict__ out) {
    int idx = blockIdx.x * 256 + threadIdx.x;
    if (idx < NNET * NUNITS) {
        float total = acc[idx] + uin[idx];
        float phi = fmaxf(total, 0.f);
        out[idx] = 0.9f * r[idx] + 0.1f * phi;
    }
}

extern "C" void kernel_launch(void* const* d_in, const int* in_sizes, int n_in,
                              void* d_out, int out_size, void* d_ws, size_t ws_size,
                              hipStream_t stream) {
    const float* unit_input = (const float*)d_in[0];
    const float* r          = (const float*)d_in[1];
    const float* W_ee       = (const float*)d_in[2];
    const float* W_ei       = (const float*)d_in[3];
    const float* W_ie       = (const float*)d_in[4];
    const float* W_ii       = (const float*)d_in[5];
    const float* W_inter    = (const float*)d_in[6];
    float* out = (float*)d_out;
    float* acc = (float*)d_ws;  // 32*2048 floats = 256 KB

    hipMemsetAsync(acc, 0, NNET * NUNITS * sizeof(float), stream);

    fused_matvec<<<3648, 256, 0, stream>>>(W_ee, W_ei, W_ie, W_ii, W_inter, r, acc);

    finalize_kernel<<<(NNET * NUNITS + 255) / 256, 256, 0, stream>>>(r, unit_input, acc, out);
}